// Round 7
// baseline (25.186 us; speedup 1.0000x reference)
//
#include <hip/hip_runtime.h>

// MakeCutouts: 32 random crops (sz in [224,511]) of a [2,3,512,512] fp32
// image, each adaptive-avg-pooled (PyTorch semantics) to 224x224.
// Output: [32*2, 3, 224, 224] fp32.
//
// R6: revert R5's XCD-affine mapping (load imbalance: per-XCD work ~ sum sz^2
// of its cutouts) and float2/parity LDS writes (8-way bank conflict).
// New structure on top of R4: ROWS=4 output rows per block. The 4 bins' input
// rows are loaded once as their union (e3-s0 ~ 4sz/224+1 rows) instead of
// sum dy (~4sz/224+4): read traffic 160->~115 MB, 4x fewer blocks, bin math
// amortized. Registers hold 4x6x2 vertical accumulators; phase 2 loops over
// the 4 rows through a double-buffered 12 KB LDS plane (stride-8 writes,
// conflict-free; barrier per row drains buf reads before its reuse at q+2).

constexpr int CUT   = 224;
constexpr int BC    = 6;          // B*C = 2*3
constexpr int HH    = 512;
constexpr int WW    = 512;
constexpr int PIX   = CUT * CUT;  // 50176
constexpr int PLANE = HH * WW;
constexpr int ROWS  = 4;          // output rows per block

__global__ __launch_bounds__(256) void cutout_kernel(
    const float* __restrict__ in,     // [6, 512, 512] planes
    const int*   __restrict__ sizes,  // [32]
    const int*   __restrict__ offx,   // [32]
    const int*   __restrict__ offy,   // [32]
    float*       __restrict__ out)    // [32, 6, 224, 224] flat
{
    __shared__ float2 vsum[2][3][WW];  // double-buffered 12 KB planes = 24 KB

    const int i0 = blockIdx.x * ROWS;  // first output row (uniform)
    const int n  = blockIdx.y;         // cutout (uniform)
    const int t  = threadIdx.x;

    const int sz = sizes[n];           // uniform -> scalar
    const int oy = offy[n];
    const int ox = offx[n];

    int sq[ROWS], eq[ROWS];            // bin row ranges (crop-relative), uniform
    #pragma unroll
    for (int q = 0; q < ROWS; ++q) {
        sq[q] = ((i0 + q) * sz) / CUT;
        eq[q] = ((i0 + q + 1) * sz + CUT - 1) / CUT;
    }
    const int s0 = sq[0];
    const int R  = eq[ROWS - 1] - s0;  // union row count, <= 11, uniform

    const bool c0 = t < sz;            // col t participates (sz >= 224)
    const bool c1 = t + 256 < sz;      // col t+256 participates

    float a[ROWS][BC], b[ROWS][BC];
    #pragma unroll
    for (int q = 0; q < ROWS; ++q)
        #pragma unroll
        for (int pl = 0; pl < BC; ++pl) { a[q][pl] = 0.f; b[q][pl] = 0.f; }

    // Phase 1: load union rows once; add each into the (<=2) bins containing it.
    const float* __restrict__ base = in + (oy + s0) * WW + ox;
    for (int r = 0; r < R; ++r) {      // uniform trip count
        const int ar = s0 + r;         // crop-relative input row, uniform
        const float* __restrict__ rp = base + r * WW;
        if (c0) {
            float v[BC];
            #pragma unroll
            for (int pl = 0; pl < BC; ++pl) v[pl] = rp[pl * PLANE + t];
            #pragma unroll
            for (int q = 0; q < ROWS; ++q)
                if (ar >= sq[q] && ar < eq[q]) {   // uniform branch
                    #pragma unroll
                    for (int pl = 0; pl < BC; ++pl) a[q][pl] += v[pl];
                }
        }
        if (c1) {
            const int u = t + 256;
            float v[BC];
            #pragma unroll
            for (int pl = 0; pl < BC; ++pl) v[pl] = rp[pl * PLANE + u];
            #pragma unroll
            for (int q = 0; q < ROWS; ++q)
                if (ar >= sq[q] && ar < eq[q]) {   // uniform branch
                    #pragma unroll
                    for (int pl = 0; pl < BC; ++pl) b[q][pl] += v[pl];
                }
        }
    }

    // Column geometry (depends only on t), computed once.
    int sx = 0, x1 = 0, x2 = 0, x3 = 0, dxc = 1;
    float w1 = 0.f, w2 = 0.f, w3 = 0.f;
    if (t < CUT) {
        sx  = (t * sz) / CUT;
        dxc = ((t + 1) * sz + CUT - 1) / CUT - sx;   // 1..4
        x1 = sx + (dxc > 1 ? 1 : 0);
        x2 = x1 + (dxc > 2 ? 1 : 0);
        x3 = x2 + (dxc > 3 ? 1 : 0);
        w1 = dxc > 1 ? 1.f : 0.f;
        w2 = dxc > 2 ? 1.f : 0.f;
        w3 = dxc > 3 ? 1.f : 0.f;
    }

    // Phase 2: per output row, stage vertical sums in LDS, pool horizontally.
    #pragma unroll
    for (int q = 0; q < ROWS; ++q) {
        float2 (*buf)[WW] = vsum[q & 1];
        if (c0) {
            buf[0][t] = make_float2(a[q][0], a[q][1]);
            buf[1][t] = make_float2(a[q][2], a[q][3]);
            buf[2][t] = make_float2(a[q][4], a[q][5]);
        }
        if (c1) {
            const int u = t + 256;
            buf[0][u] = make_float2(b[q][0], b[q][1]);
            buf[1][u] = make_float2(b[q][2], b[q][3]);
            buf[2][u] = make_float2(b[q][4], b[q][5]);
        }
        __syncthreads();
        if (t < CUT) {
            const int dy = eq[q] - sq[q];
            const float rr = __builtin_amdgcn_rcpf((float)(dy * dxc));
            float* o = out + (size_t)n * BC * PIX + (i0 + q) * CUT + t;
            #pragma unroll
            for (int pr = 0; pr < 3; ++pr) {
                const float2 v0 = buf[pr][sx];
                const float2 v1 = buf[pr][x1];
                const float2 v2 = buf[pr][x2];
                const float2 v3 = buf[pr][x3];
                const float se = v0.x + w1 * v1.x + w2 * v2.x + w3 * v3.x;
                const float so = v0.y + w1 * v1.y + w2 * v2.y + w3 * v3.y;
                __builtin_nontemporal_store(se * rr, o + (2 * pr    ) * PIX);
                __builtin_nontemporal_store(so * rr, o + (2 * pr + 1) * PIX);
            }
        }
    }
}

extern "C" void kernel_launch(void* const* d_in, const int* in_sizes, int n_in,
                              void* d_out, int out_size, void* d_ws, size_t ws_size,
                              hipStream_t stream) {
    const float* in    = (const float*)d_in[0];
    const int*   sizes = (const int*)d_in[1];
    const int*   offx  = (const int*)d_in[2];
    const int*   offy  = (const int*)d_in[3];
    float*       out   = (float*)d_out;

    cutout_kernel<<<dim3(CUT / ROWS, 32), dim3(256), 0, stream>>>(
        in, sizes, offx, offy, out);
}

// Round 8
// 21.343 us; speedup vs baseline: 1.1801x; 1.1801x over previous
//
#include <hip/hip_runtime.h>

// MakeCutouts: 32 random crops (sz in [224,511]) of a [2,3,512,512] fp32
// image, each adaptive-avg-pooled (PyTorch semantics) to 224x224.
// Output: [32*2, 3, 224, 224] fp32.
//
// R7 = R4 (best known, 20.9us) with phase 1's runtime dy-loop (1..4 trips,
// ~2.6 SERIALIZED load->wait round-trips per block since the compiler can't
// unroll unknown trip counts) replaced by 4 predicated vertical taps with
// clamped row offsets: loads issue in bursts (one wait per 3-plane group).
// Masked taps re-read the previous tap's row -> same cachelines -> L1 hits,
// so effective memory traffic is unchanged; only the instruction count rises.
// R5/R6 lessons: traffic reduction (-28%) regressed both times -> R4 is
// latency-bound, not traffic-bound; keep its grid/LDS/store structure.

constexpr int CUT   = 224;
constexpr int BC    = 6;          // B*C = 2*3
constexpr int HH    = 512;
constexpr int WW    = 512;
constexpr int PIX   = CUT * CUT;  // 50176
constexpr int PLANE = HH * WW;

__global__ __launch_bounds__(256) void cutout_kernel(
    const float* __restrict__ in,     // [6, 512, 512] planes
    const int*   __restrict__ sizes,  // [32]
    const int*   __restrict__ offx,   // [32]
    const int*   __restrict__ offy,   // [32]
    float*       __restrict__ out)    // [32, 6, 224, 224] flat
{
    __shared__ float2 vsum[3][WW];    // [plane-pair][crop col] = 12 KB

    const int i = blockIdx.x;         // output row (uniform)
    const int n = blockIdx.y;         // cutout (uniform)
    const int t = threadIdx.x;

    const int sz = sizes[n];          // uniform -> scalar
    const int oy = offy[n];
    const int ox = offx[n];

    const int sy = (i * sz) / CUT;                        // uniform
    const int dy = ((i + 1) * sz + CUT - 1) / CUT - sy;   // 1..4, uniform

    // Predicated vertical taps: clamped row offsets (masked tap re-reads the
    // previous valid row -> L1 hit), {0,1} weights. All uniform.
    const int r1 = (dy > 1 ? WW : 0);
    const int r2 = r1 + (dy > 2 ? WW : 0);
    const int r3 = r2 + (dy > 3 ? WW : 0);
    const float wv1 = dy > 1 ? 1.f : 0.f;
    const float wv2 = dy > 2 ? 1.f : 0.f;
    const float wv3 = dy > 3 ? 1.f : 0.f;

    const float* __restrict__ base = in + (oy + sy) * WW + ox;
    const bool c0 = t < sz;           // sz >= 224; only lanes 224..255 can fail
    const bool c1 = t + 256 < sz;

    float va[BC], vb[BC];
    #pragma unroll
    for (int g = 0; g < 2; ++g) {     // plane groups {0,1,2}, {3,4,5}
        const float* __restrict__ pg = base + g * 3 * PLANE;
        if (c0) {
            float x00,x01,x02,x03, x10,x11,x12,x13, x20,x21,x22,x23;
            x00 = pg[0*PLANE + t];      x10 = pg[1*PLANE + t];      x20 = pg[2*PLANE + t];
            x01 = pg[0*PLANE + r1 + t]; x11 = pg[1*PLANE + r1 + t]; x21 = pg[2*PLANE + r1 + t];
            x02 = pg[0*PLANE + r2 + t]; x12 = pg[1*PLANE + r2 + t]; x22 = pg[2*PLANE + r2 + t];
            x03 = pg[0*PLANE + r3 + t]; x13 = pg[1*PLANE + r3 + t]; x23 = pg[2*PLANE + r3 + t];
            va[3*g + 0] = x00 + wv1*x01 + wv2*x02 + wv3*x03;
            va[3*g + 1] = x10 + wv1*x11 + wv2*x12 + wv3*x13;
            va[3*g + 2] = x20 + wv1*x21 + wv2*x22 + wv3*x23;
        }
        if (c1) {
            const int u = t + 256;
            float y00,y01,y02,y03, y10,y11,y12,y13, y20,y21,y22,y23;
            y00 = pg[0*PLANE + u];      y10 = pg[1*PLANE + u];      y20 = pg[2*PLANE + u];
            y01 = pg[0*PLANE + r1 + u]; y11 = pg[1*PLANE + r1 + u]; y21 = pg[2*PLANE + r1 + u];
            y02 = pg[0*PLANE + r2 + u]; y12 = pg[1*PLANE + r2 + u]; y22 = pg[2*PLANE + r2 + u];
            y03 = pg[0*PLANE + r3 + u]; y13 = pg[1*PLANE + r3 + u]; y23 = pg[2*PLANE + r3 + u];
            vb[3*g + 0] = y00 + wv1*y01 + wv2*y02 + wv3*y03;
            vb[3*g + 1] = y10 + wv1*y11 + wv2*y12 + wv3*y13;
            vb[3*g + 2] = y20 + wv1*y21 + wv2*y22 + wv3*y23;
        }
    }

    if (c0) {
        vsum[0][t] = make_float2(va[0], va[1]);
        vsum[1][t] = make_float2(va[2], va[3]);
        vsum[2][t] = make_float2(va[4], va[5]);
    }
    if (c1) {
        const int u = t + 256;
        vsum[0][u] = make_float2(vb[0], vb[1]);
        vsum[1][u] = make_float2(vb[2], vb[3]);
        vsum[2][u] = make_float2(vb[4], vb[5]);
    }
    __syncthreads();

    // Phase 2: horizontal pooling from LDS, 4 predicated taps (dx in 1..4).
    if (t < CUT) {
        const int sx = (t * sz) / CUT;                        // crop-relative
        const int dx = ((t + 1) * sz + CUT - 1) / CUT - sx;   // 1..4
        const int x1 = sx + (dx > 1 ? 1 : 0);                 // clamped taps
        const int x2 = x1 + (dx > 2 ? 1 : 0);
        const int x3 = x2 + (dx > 3 ? 1 : 0);
        const float w1 = dx > 1 ? 1.f : 0.f;
        const float w2 = dx > 2 ? 1.f : 0.f;
        const float w3 = dx > 3 ? 1.f : 0.f;
        const float rr = __builtin_amdgcn_rcpf((float)(dy * dx));

        float* o = out + (size_t)n * BC * PIX + i * CUT + t;
        #pragma unroll
        for (int pr = 0; pr < 3; ++pr) {
            const float2 v0 = vsum[pr][sx];
            const float2 v1 = vsum[pr][x1];
            const float2 v2 = vsum[pr][x2];
            const float2 v3 = vsum[pr][x3];
            const float se = v0.x + w1 * v1.x + w2 * v2.x + w3 * v3.x;
            const float so = v0.y + w1 * v1.y + w2 * v2.y + w3 * v3.y;
            __builtin_nontemporal_store(se * rr, o + (2 * pr    ) * PIX);
            __builtin_nontemporal_store(so * rr, o + (2 * pr + 1) * PIX);
        }
    }
}

extern "C" void kernel_launch(void* const* d_in, const int* in_sizes, int n_in,
                              void* d_out, int out_size, void* d_ws, size_t ws_size,
                              hipStream_t stream) {
    const float* in    = (const float*)d_in[0];
    const int*   sizes = (const int*)d_in[1];
    const int*   offx  = (const int*)d_in[2];
    const int*   offy  = (const int*)d_in[3];
    float*       out   = (float*)d_out;

    cutout_kernel<<<dim3(CUT, 32), dim3(256), 0, stream>>>(
        in, sizes, offx, offy, out);
}